// Round 4
// baseline (77.676 us; speedup 1.0000x reference)
//
#include <hip/hip_runtime.h>

#define Bsz 128
#define Csz 1024
#define Nsz 512
#define NCsz 1024
#define CAPT 96    // max combined literals/clause; E=20.5, sd~6.3 -> 96 is ~12 sigma

// ---------------- Kernel 1: clause scan -> transposed combined literal list + head ------
// 256 blocks x 256 thr, 1 clause per wave (round-0-verified wave-ordered LDS counter).
// litT[s][c] = (n<<1)|isneg  (transposed: k2's per-clause literal loop is c-coalesced).
__global__ __launch_bounds__(256) void k_scan(
    const float* __restrict__ pos_head, const float* __restrict__ neg_head,
    const float* __restrict__ pos_body, const float* __restrict__ neg_body,
    int* __restrict__ litT, int* __restrict__ lit_cnt, int* __restrict__ head_of)
{
    __shared__ int cnts[4];
    int tid = threadIdx.x;
    int wave = tid >> 6, lane = tid & 63;
    int c = blockIdx.x * 4 + wave;
    if (lane == 0) cnts[wave] = 0;
    // per-wave LDS counter, wave-ordered stream: no barrier needed
    const float4* pb4 = (const float4*)(pos_body + c * Nsz);
    const float4* nb4 = (const float4*)(neg_body + c * Nsz);
    const float4* ph4 = (const float4*)(pos_head + c * Nsz);
    const float4* nh4 = (const float4*)(neg_head + c * Nsz);
    for (int k = 0; k < 2; k++) {
        int q = k * 64 + lane;                 // float4 index, n0 = 4*q
        float4 p  = pb4[q];
        float4 nb = nb4[q];
        float4 ph = ph4[q];
        float4 nh = nh4[q];
        int n0 = q * 4;
        if (p.x  != 0.f) { int s = atomicAdd(&cnts[wave], 1); if (s < CAPT) litT[s * Csz + c] = (n0    ) << 1; }
        if (p.y  != 0.f) { int s = atomicAdd(&cnts[wave], 1); if (s < CAPT) litT[s * Csz + c] = (n0 + 1) << 1; }
        if (p.z  != 0.f) { int s = atomicAdd(&cnts[wave], 1); if (s < CAPT) litT[s * Csz + c] = (n0 + 2) << 1; }
        if (p.w  != 0.f) { int s = atomicAdd(&cnts[wave], 1); if (s < CAPT) litT[s * Csz + c] = (n0 + 3) << 1; }
        if (nb.x != 0.f) { int s = atomicAdd(&cnts[wave], 1); if (s < CAPT) litT[s * Csz + c] = ((n0    ) << 1) | 1; }
        if (nb.y != 0.f) { int s = atomicAdd(&cnts[wave], 1); if (s < CAPT) litT[s * Csz + c] = ((n0 + 1) << 1) | 1; }
        if (nb.z != 0.f) { int s = atomicAdd(&cnts[wave], 1); if (s < CAPT) litT[s * Csz + c] = ((n0 + 2) << 1) | 1; }
        if (nb.w != 0.f) { int s = atomicAdd(&cnts[wave], 1); if (s < CAPT) litT[s * Csz + c] = ((n0 + 3) << 1) | 1; }
        if (ph.x != 0.f) head_of[c] = ((n0    ) << 1) | 1;
        if (ph.y != 0.f) head_of[c] = ((n0 + 1) << 1) | 1;
        if (ph.z != 0.f) head_of[c] = ((n0 + 2) << 1) | 1;
        if (ph.w != 0.f) head_of[c] = ((n0 + 3) << 1) | 1;
        if (nh.x != 0.f) head_of[c] = ((n0    ) << 1);
        if (nh.y != 0.f) head_of[c] = ((n0 + 1) << 1);
        if (nh.z != 0.f) head_of[c] = ((n0 + 2) << 1);
        if (nh.w != 0.f) head_of[c] = ((n0 + 3) << 1);
    }
    if (lane == 0) lit_cnt[c] = min(cnts[wave], CAPT);
}

// ---------------- Kernel 2: per-batch-row everything, bounds in LDS ----------------
// 128 blocks (one per b) x 1024 threads. Phases inside one block (__syncthreads only):
//  1. gather m[n] = preds[b][atoms[n]] into LDS; build inv[j] table; zero lb/ub
//  2. thread=clause: body_min over litT (c-coalesced loads, LDS m lookups)
//     -> LDS atomicMax (float-bits, bm in [0,1]) into lbq/ubq[head]
//  3. write full out row coalesced: clamp atom cols via inv[], pass-through otherwise
// No global bounds buffer, no zero-fill, no third kernel.
__global__ __launch_bounds__(1024) void k_apply(
    const float* __restrict__ preds,
    const int* __restrict__ atoms,
    const int* __restrict__ litT, const int* __restrict__ lit_cnt,
    const int* __restrict__ head_of,
    float* __restrict__ out)
{
    __shared__ float    m[Nsz];
    __shared__ unsigned lbq[Nsz];
    __shared__ unsigned ubq[Nsz];
    __shared__ short    inv[NCsz];

    const int b = blockIdx.x, tid = threadIdx.x;

    // ---- phase 1: init + gather ----
    inv[tid] = -1;                            // 1024 threads == NCsz
    if (tid < Nsz) { lbq[tid] = 0u; ubq[tid] = 0u; }
    __syncthreads();
    if (tid < Nsz) {
        int a = atoms[tid];
        m[tid] = preds[b * NCsz + a];         // row-local gather, L1/L2-resident
        inv[a] = (short)tid;
    }
    __syncthreads();

    // ---- phase 2: one clause per thread ----
    {
        int c = tid;                          // Csz == 1024 == blockDim
        int cnt = lit_cnt[c];
        float acc = 0.f;
        #pragma unroll 4
        for (int e = 0; e < cnt; e++) {
            int v = litT[e * Csz + c];        // coalesced across threads for each e
            float x = m[v >> 1];
            acc = fmaxf(acc, (v & 1) ? x : 1.f - x);
        }
        float bm = 1.f - acc;                 // body_min in [0,1]
        int h = head_of[c];
        unsigned* dst = (h & 1) ? lbq : ubq;  // pos head -> lb, neg head -> ub
        atomicMax(&dst[h >> 1], __float_as_uint(bm));
    }
    __syncthreads();

    // ---- phase 3: full row write ----
    {
        float v = preds[b * NCsz + tid];
        int n = inv[tid];
        if (n >= 0) {
            float lb = __uint_as_float(lbq[n]);
            float ub = 1.f - __uint_as_float(ubq[n]);
            float lo = fminf(lb, ub), hi = fmaxf(lb, ub);
            v = fmaxf(lo, fminf(hi, v));      // deg-0 atom: lb=0, ub=1 -> identity
        }
        out[b * NCsz + tid] = v;
    }
}

extern "C" void kernel_launch(void* const* d_in, const int* in_sizes, int n_in,
                              void* d_out, int out_size, void* d_ws, size_t ws_size,
                              hipStream_t stream)
{
    const float* preds    = (const float*)d_in[0];
    const float* pos_head = (const float*)d_in[1];
    const float* neg_head = (const float*)d_in[2];
    const float* pos_body = (const float*)d_in[3];
    const float* neg_body = (const float*)d_in[4];
    const int*   atoms    = (const int*)d_in[5];
    float* out = (float*)d_out;

    char* ws = (char*)d_ws;
    int* litT    = (int*)(ws);                        // CAPT * Csz = 98304 ints (~393 KB)
    int* lit_cnt = (int*)(ws + (size_t)CAPT * Csz * 4);
    int* head_of = lit_cnt + Csz;

    k_scan<<<256, 256, 0, stream>>>(pos_head, neg_head, pos_body, neg_body,
                                    litT, lit_cnt, head_of);

    k_apply<<<Bsz, 1024, 0, stream>>>(preds, atoms, litT, lit_cnt, head_of, out);
}